// Round 33
// baseline (516.944 us; speedup 1.0000x reference)
//
#include <hip/hip_runtime.h>
#include <hip/hip_bf16.h>

#define DEV __device__ __forceinline__

static DEV float lrelu(float v) { return v >= 0.f ? v : 0.01f * v; }
static DEV float bflo(unsigned u) { return __uint_as_float(u << 16); }
static DEV float bfhi(unsigned u) { return __uint_as_float(u & 0xffff0000u); }
static DEV unsigned short f2bf(float f) {
  unsigned u = __float_as_uint(f);
  return (unsigned short)((u + 0x7FFF + ((u >> 16) & 1)) >> 16);  // RNE
}
static DEV unsigned pk(float a, float b) {
  return (unsigned)f2bf(a) | ((unsigned)f2bf(b) << 16);
}

constexpr int BATCH = 256;

// ---- compact workspace layout (bytes) ----
constexpr size_t BYTE_B = 13107200;
constexpr size_t BYTE_C = 18350080;
constexpr size_t BYTE_D = 19398656;

// ---------------------------------------------------------------- k1 v9 (y-merge + shuffle pool)
// R30 cost model applied in reverse: 4 conv rows/block (grid (B,25)) cuts halo
// amplification 2.0x -> 1.5x and halves per-block fixed costs; pool done
// in-register via shfl_xor (lane^1 = cy pair, lane^2 = cx pair) -- drops the
// pc LDS buffer, one barrier, and the 192-idle-thread pool stage.
__global__ __launch_bounds__(256, 1) void k1_conv1_pool(
    const float* __restrict__ x, const float* __restrict__ w1,
    const float* __restrict__ b1, __hip_bfloat16* __restrict__ p1) {
  __shared__ uint4 xs[6 * 132];      // 6 rows x 130(+2 pad) pos x 6ch bf16, 12672 B
  __shared__ float wsh[576];         // [k9][co8][ci8] f32 (ci 6,7 zero), 2304 B
  __shared__ float bsh[8];
  const int b = blockIdx.x, yt = blockIdx.y, tid = threadIdx.x;
  for (int i = tid; i < 576; i += 256) {
    const int ci = i & 7, co = (i >> 3) & 7, k = i >> 6;
    wsh[i] = (ci < 6) ? w1[(co * 6 + ci) * 9 + k] : 0.f;
  }
  if (tid < 8) bsh[tid] = b1[tid];
  for (int p = tid; p < 780; p += 256) {
    const int lx = p % 130, ly = p / 130;
    const int gy = 4 * yt - 1 + ly, gx = lx - 1;
    float v[6];
    if ((unsigned)gy < 100u && (unsigned)gx < 128u) {
      #pragma unroll
      for (int c = 0; c < 6; ++c) v[c] = x[((size_t)(b * 6 + c) * 100 + gy) * 128 + gx];
    } else {
      #pragma unroll
      for (int c = 0; c < 6; ++c) v[c] = 0.f;
    }
    xs[ly * 132 + lx] = make_uint4(pk(v[0], v[1]), pk(v[2], v[3]), pk(v[4], v[5]), 0u);
  }
  __syncthreads();
  {
    const int pp = tid & 1, cx = tid >> 1;   // cy parity, conv x
    #pragma unroll
    for (int r = 0; r < 2; ++r) {
      const int cy = 2 * r + pp;             // conv row 0..3 (xs row cy..cy+2)
      float ev[8];
      #pragma unroll
      for (int co = 0; co < 8; ++co) ev[co] = bsh[co];
      #pragma unroll
      for (int k = 0; k < 9; ++k) {
        const int ky = k / 3, kx = k % 3;
        const uint4 q = xs[(cy + ky) * 132 + (cx + kx)];
        const float i0 = bflo(q.x), i1 = bfhi(q.x);
        const float i2 = bflo(q.y), i3 = bfhi(q.y);
        const float i4 = bflo(q.z), i5 = bfhi(q.z);
        #pragma unroll
        for (int co = 0; co < 8; ++co) {
          const float4 wlo = *(const float4*)&wsh[(k * 8 + co) * 8];    // wave-uniform f32
          const float2 whi = *(const float2*)&wsh[(k * 8 + co) * 8 + 4];
          float a = ev[co];
          a += i0 * wlo.x; a += i1 * wlo.y;
          a += i2 * wlo.z; a += i3 * wlo.w;
          a += i4 * whi.x; a += i5 * whi.y;
          ev[co] = a;
        }
      }
      float m[8];
      #pragma unroll
      for (int co = 0; co < 8; ++co) {
        float v0 = lrelu(ev[co]);
        float v1 = fmaxf(v0, __shfl_xor(v0, 1, 64));   // cy pair
        m[co] = fmaxf(v1, __shfl_xor(v1, 2, 64));      // cx pair
      }
      if ((tid & 3) == 0) {
        const int ox = tid >> 2;
        const int Y = 2 * yt + r;
        #pragma unroll
        for (int co = 0; co < 8; ++co)
          p1[((size_t)(b * 8 + co) * 50 + Y) * 64 + ox] = __float2bfloat16(m[co]);
      }
    }
  }
}

// ---------------------------------------------------------------- k2 v2b (REVERTED from v3)
// v3 (bf16 tile, no swizzle) regressed +13us: stage-2 lane-stride is 2
// positions (not 1 like k7), so the unswizzled 16B layout conflicts.
__global__ __launch_bounds__(256, 1) void k2_conv2_pool(
    const __hip_bfloat16* __restrict__ p1, const float* __restrict__ w2,
    const float* __restrict__ b2, float* __restrict__ p2) {
  __shared__ float4 s1[1904];        // 7 * 272 float4 = 30464 B
  __shared__ float wsh[1152];        // [k9][co16][ci8]
  __shared__ float bsh[16];
  const int b = blockIdx.x, yt = blockIdx.y, tid = threadIdx.x;
  for (int i = tid; i < 1152; i += 256) {
    const int ci = i & 7, co = (i >> 3) & 15, k = i >> 7;
    wsh[i] = w2[(co * 8 + ci) * 9 + k];
  }
  if (tid < 16) bsh[tid] = b2[tid];
  for (int p = tid; p < 462; p += 256) {
    const int lx = p % 66, ly = p / 66;
    const int gy = 5 * yt - 1 + ly, gx = lx - 1;
    float v[8];
    if ((unsigned)gy < 50u && (unsigned)gx < 64u) {
      #pragma unroll
      for (int c = 0; c < 8; ++c)
        v[c] = __bfloat162float(p1[((size_t)(b * 8 + c) * 50 + gy) * 64 + gx]);
    } else {
      #pragma unroll
      for (int c = 0; c < 8; ++c) v[c] = 0.f;
    }
    const int base = ly * 4352;   // 136 positions * 32 B stride
    const int sw = (((lx >> 2) & 7) << 4) ^ ((ly & 1) << 4);
    *(float4*)((char*)s1 + base + ((lx * 32) ^ sw)) = make_float4(v[0], v[1], v[2], v[3]);
    *(float4*)((char*)s1 + base + ((lx * 32 + 16) ^ sw)) = make_float4(v[4], v[5], v[6], v[7]);
  }
  __syncthreads();
  {
    const int ox = tid & 31, cog = tid >> 5;   // co pair {2cog, 2cog+1}
    const int co0 = cog * 2;
    float ev[2][5][2];
    #pragma unroll
    for (int j = 0; j < 2; ++j) {
      const float bv = bsh[co0 + j];
      #pragma unroll
      for (int dy = 0; dy < 5; ++dy) { ev[j][dy][0] = bv; ev[j][dy][1] = bv; }
    }
    #pragma unroll
    for (int k = 0; k < 9; ++k) {
      const int ky = k / 3, kx = k % 3;
      float wr[2][8];
      #pragma unroll
      for (int j = 0; j < 2; ++j) {
        const float4 lo = *(const float4*)&wsh[(k * 16 + co0 + j) * 8];
        const float4 hi = *(const float4*)&wsh[(k * 16 + co0 + j) * 8 + 4];
        wr[j][0] = lo.x; wr[j][1] = lo.y; wr[j][2] = lo.z; wr[j][3] = lo.w;
        wr[j][4] = hi.x; wr[j][5] = hi.y; wr[j][6] = hi.z; wr[j][7] = hi.w;
      }
      #pragma unroll
      for (int dy = 0; dy < 5; ++dy) {
        const int lr = dy + ky;
        const int base = lr * 4352;
        const int rsw = (lr & 1) << 4;
        float in2[2][8];
        #pragma unroll
        for (int dx = 0; dx < 2; ++dx) {
          const int lc = 2 * ox + dx + kx;
          const int sw = (((lc >> 2) & 7) << 4) ^ rsw;
          const float4 lo = *(const float4*)((const char*)s1 + base + ((lc * 32) ^ sw));
          const float4 hi = *(const float4*)((const char*)s1 + base + ((lc * 32 + 16) ^ sw));
          in2[dx][0] = lo.x; in2[dx][1] = lo.y; in2[dx][2] = lo.z; in2[dx][3] = lo.w;
          in2[dx][4] = hi.x; in2[dx][5] = hi.y; in2[dx][6] = hi.z; in2[dx][7] = hi.w;
        }
        #pragma unroll
        for (int j = 0; j < 2; ++j)
          #pragma unroll
          for (int dx = 0; dx < 2; ++dx)
            #pragma unroll
            for (int ci = 0; ci < 8; ++ci)
              ev[j][dy][dx] += in2[dx][ci] * wr[j][ci];
      }
    }
    #pragma unroll
    for (int j = 0; j < 2; ++j) {
      float m = -1e30f;
      #pragma unroll
      for (int dy = 0; dy < 5; ++dy)
        #pragma unroll
        for (int dx = 0; dx < 2; ++dx)
          m = fmaxf(m, lrelu(ev[j][dy][dx]));
      p2[((size_t)(b * 16 + co0 + j) * 10 + yt) * 32 + ox] = m;
    }
  }
}

// ---------------------------------------------------------------- k3 v2 (unchanged)
__global__ __launch_bounds__(256) void k3_conv3_pool(
    const float* __restrict__ p2, const float* __restrict__ w3,
    const float* __restrict__ b3, float* __restrict__ p3) {
  __shared__ float s2[16][7][34];    // p2 rows 5oh-1 .. 5oh+5, 15232 B
  __shared__ float wsh[4608];
  __shared__ float bsh[32];
  const int b = blockIdx.x, oh = blockIdx.y, tid = threadIdx.x;
  for (int i = tid; i < 4608; i += 256) wsh[i] = w3[i];
  if (tid < 32) bsh[tid] = b3[tid];
  for (int i = tid; i < 16 * 7 * 34; i += 256) {
    int col = i % 34, rem = i / 34, r = rem % 7, c = rem / 7;
    int gy = 5 * oh - 1 + r, gx = col - 1;
    float v = 0.f;
    if ((unsigned)gy < 10u && (unsigned)gx < 32u)
      v = p2[((b * 16 + c) * 10 + gy) * 32 + gx];
    s2[c][r][col] = v;
  }
  __syncthreads();
  for (int i = tid; i < 512; i += 256) {
    int ow = i & 15, co = i >> 4;
    float m = -1e30f;
    for (int dy = 0; dy < 5; ++dy)
      #pragma unroll
      for (int dx = 0; dx < 2; ++dx) {
        int cx = 2 * ow + dx;
        float acc = bsh[co];
        #pragma unroll
        for (int ci = 0; ci < 16; ++ci)
          #pragma unroll
          for (int ky = 0; ky < 3; ++ky)
            #pragma unroll
            for (int kx = 0; kx < 3; ++kx)
              acc += s2[ci][dy + ky][cx + kx] * wsh[(co * 16 + ci) * 9 + ky * 3 + kx];
        m = fmaxf(m, lrelu(acc));
      }
    p3[((b * 32 + co) * 2 + oh) * 16 + ow] = m;
  }
}

// ---------------------------------------------------------------- k4 (unchanged)
__global__ __launch_bounds__(64) void k4_latent(
    const float* __restrict__ p3, const float* __restrict__ eps,
    const float* __restrict__ wmu, const float* __restrict__ bmu,
    const float* __restrict__ wlv, const float* __restrict__ blv,
    const float* __restrict__ wlin, const float* __restrict__ blin,
    float* __restrict__ dec, float* __restrict__ out,
    size_t off_mu, size_t off_lv, size_t off_kld, size_t off_z) {
  const int b = blockIdx.x, t = threadIdx.x;
  __shared__ float skld[32];
  if (t < 32) {
    const int h = t >> 4, w = t & 15;
    float f[32];
    #pragma unroll
    for (int c = 0; c < 32; ++c) f[c] = p3[((b * 32 + c) * 2 + h) * 16 + w];
    const int n = b * 32 + t;
    float mu[4], lv[4], zz[4];
    #pragma unroll
    for (int j = 0; j < 4; ++j) {
      float m = bmu[j], l = blv[j];
      #pragma unroll
      for (int c = 0; c < 32; ++c) { m += f[c] * wmu[c * 4 + j]; l += f[c] * wlv[c * 4 + j]; }
      mu[j] = m; lv[j] = l;
      zz[j] = m + eps[n * 4 + j] * expf(0.5f * l);
    }
    float kc = 0.f;
    #pragma unroll
    for (int j = 0; j < 4; ++j) kc += 1.f + lv[j] - mu[j] * mu[j] - expf(lv[j]);
    skld[t] = -0.5f * kc;
    #pragma unroll
    for (int j = 0; j < 4; ++j) {
      out[off_mu + n * 4 + j] = mu[j];
      out[off_lv + n * 4 + j] = lv[j];
      out[off_z  + n * 4 + j] = zz[j];
    }
    for (int co = 0; co < 32; ++co) {
      float d = blin[co];
      #pragma unroll
      for (int j = 0; j < 4; ++j) d += zz[j] * wlin[j * 32 + co];
      dec[((b * 32 + co) * 2 + h) * 16 + w] = d;
    }
  }
  __syncthreads();
  if (t == 0) {
    float s = 0.f;
    for (int i = 0; i < 32; ++i) s += skld[i];
    out[off_kld + b] = s * (1.f / 32.f);
  }
}

// ---------------------------------------------------------------- k5 v2 (unchanged)
__global__ __launch_bounds__(256) void k5_inv1_conv4(
    const float* __restrict__ dec, const float* __restrict__ wi1,
    const float* __restrict__ bi1, const float* __restrict__ w4,
    const float* __restrict__ b4, float* __restrict__ h4) {
  __shared__ float sdec[1024];       // dec [32][2][16] f32, 4 KB
  __shared__ float su1[32][7][34];   // u1 rows y0-1..y0+5 (+x halo), 30464 B
  const int b = blockIdx.x, yt = blockIdx.y, tid = threadIdx.x;
  const int y0 = 5 * yt;
  for (int i = tid; i < 1024; i += 256) sdec[i] = dec[b * 1024 + i];
  __syncthreads();
  for (int i = tid; i < 32 * 7 * 34; i += 256) {
    int col = i % 34, rem = i / 34, ly = rem % 7, c = rem / 7;
    int X = col - 1, Y = y0 - 1 + ly;
    float v = 0.f;
    if ((unsigned)Y < 10u && (unsigned)X < 32u) {
      int hh = Y / 5, ky = Y % 5, wp = X >> 1, kx = X & 1;
      float acc = bi1[c];
      #pragma unroll
      for (int ci = 0; ci < 32; ++ci)
        acc += sdec[(ci * 2 + hh) * 16 + wp] * wi1[((ci * 32 + c) * 5 + ky) * 2 + kx];
      v = lrelu(acc);
    }
    su1[c][ly][col] = v;
  }
  __syncthreads();
  for (int i = tid; i < 16 * 5 * 32; i += 256) {
    int X = i & 31, rem = i >> 5, rr = rem % 5, o = rem / 5;
    float acc = b4[o];
    for (int c = 0; c < 32; ++c)
      #pragma unroll
      for (int ky = 0; ky < 3; ++ky)
        #pragma unroll
        for (int kx = 0; kx < 3; ++kx)
          acc += su1[c][rr + ky][X + kx] * w4[((o * 32 + c) * 3 + ky) * 3 + kx];
    h4[((b * 16 + o) * 10 + y0 + rr) * 32 + X] = lrelu(acc);
  }
}

// ---------------------------------------------------------------- k6 v6 (best, unchanged)
__global__ __launch_bounds__(256, 1) void k6_inv2_conv5(
    const float* __restrict__ h4, const float* __restrict__ wi2,
    const float* __restrict__ bi2, const float* __restrict__ w5,
    const float* __restrict__ b5, __hip_bfloat16* __restrict__ h5) {
  __shared__ uint4 su[924];           // u2 bf16 ch-last [7][66][16], swizzled, 14784 B
  __shared__ unsigned sh4b[3][32][12];// h4 ch-last bf16 pairs (8 used + 4 pad), 4608 B
  __shared__ unsigned wcl[1280];      // wi2 bf16 pairs [ci16][tap10][cp8], 5120 B
  __shared__ unsigned w5b[576];       // w5 bf16 pairs [k9][o8][cp8], 2304 B
  const int b = blockIdx.x, yt = blockIdx.y, tid = threadIdx.x;
  const int y0 = 5 * yt;
  const int r0 = (yt == 0) ? 0 : (yt - 1);
  for (int i = tid; i < 768; i += 256) {
    const int cp = i & 7, hc = (i >> 3) & 31, r = i >> 8;
    const int gr = r0 + r;
    const int c0 = cp * 2;
    float va = 0.f, vb = 0.f;
    if (gr < 10) {
      va = h4[((b * 16 + c0) * 10 + gr) * 32 + hc];
      vb = h4[((b * 16 + c0 + 1) * 10 + gr) * 32 + hc];
    }
    sh4b[r][hc][cp] = pk(va, vb);
  }
  for (int i = tid; i < 1280; i += 256) {
    const int cp = i & 7, ci = (i >> 3) & 15, tap = i >> 7;
    const int ky = tap >> 1, kx = tap & 1;
    const int c0 = cp * 2;
    const float wa = wi2[((ci * 16 + c0) * 5 + ky) * 2 + kx];
    const float wb = wi2[((ci * 16 + c0 + 1) * 5 + ky) * 2 + kx];
    wcl[(ci * 10 + tap) * 8 + cp] = pk(wa, wb);   // [ci][tap][cp]
  }
  for (int i = tid; i < 576; i += 256) {
    const int cp = i & 7, o = (i >> 3) & 7, k = i >> 6;
    const int c0 = cp * 2;
    w5b[i] = pk(w5[((o * 16 + c0) * 3 + (k / 3)) * 3 + (k % 3)],
                w5[((o * 16 + c0 + 1) * 3 + (k / 3)) * 3 + (k % 3)]);
  }
  __syncthreads();
  for (int pos = tid; pos < 462; pos += 256) {
    const int lx = pos % 66, ly = pos / 66;
    const int Y = y0 - 1 + ly, X = lx - 1;
    float u[16];
    if ((unsigned)Y < 50u && (unsigned)X < 64u) {
      const int hr = Y / 5 - r0, ky = Y % 5, hc = X >> 1, kx = X & 1;
      const int tap = ky * 2 + kx;
      #pragma unroll
      for (int c = 0; c < 16; ++c) u[c] = bi2[c];
      float hv[16];
      {
        const uint4 t0 = *(const uint4*)&sh4b[hr][hc][0];
        const uint4 t1 = *(const uint4*)&sh4b[hr][hc][4];
        hv[0]  = bflo(t0.x); hv[1]  = bfhi(t0.x);
        hv[2]  = bflo(t0.y); hv[3]  = bfhi(t0.y);
        hv[4]  = bflo(t0.z); hv[5]  = bfhi(t0.z);
        hv[6]  = bflo(t0.w); hv[7]  = bfhi(t0.w);
        hv[8]  = bflo(t1.x); hv[9]  = bfhi(t1.x);
        hv[10] = bflo(t1.y); hv[11] = bfhi(t1.y);
        hv[12] = bflo(t1.z); hv[13] = bfhi(t1.z);
        hv[14] = bflo(t1.w); hv[15] = bfhi(t1.w);
      }
      #pragma unroll
      for (int ci = 0; ci < 16; ++ci) {
        const uint4 wq0 = *(const uint4*)&wcl[(ci * 10 + tap) * 8];      // [ci][tap]
        const uint4 wq1 = *(const uint4*)&wcl[(ci * 10 + tap) * 8 + 4];
        const float h = hv[ci];
        u[0]  += h * bflo(wq0.x); u[1]  += h * bfhi(wq0.x);
        u[2]  += h * bflo(wq0.y); u[3]  += h * bfhi(wq0.y);
        u[4]  += h * bflo(wq0.z); u[5]  += h * bfhi(wq0.z);
        u[6]  += h * bflo(wq0.w); u[7]  += h * bfhi(wq0.w);
        u[8]  += h * bflo(wq1.x); u[9]  += h * bfhi(wq1.x);
        u[10] += h * bflo(wq1.y); u[11] += h * bfhi(wq1.y);
        u[12] += h * bflo(wq1.z); u[13] += h * bfhi(wq1.z);
        u[14] += h * bflo(wq1.w); u[15] += h * bfhi(wq1.w);
      }
      #pragma unroll
      for (int c = 0; c < 16; ++c) u[c] = lrelu(u[c]);
    } else {
      #pragma unroll
      for (int c = 0; c < 16; ++c) u[c] = 0.f;
    }
    const int sw = (((lx >> 2) & 7) << 4) ^ ((ly & 1) << 4);
    *(uint4*)((char*)su + ly * 2112 + ((lx * 32) ^ sw)) =
        make_uint4(pk(u[0], u[1]), pk(u[2], u[3]), pk(u[4], u[5]), pk(u[6], u[7]));
    *(uint4*)((char*)su + ly * 2112 + ((lx * 32 + 16) ^ sw)) =
        make_uint4(pk(u[8], u[9]), pk(u[10], u[11]), pk(u[12], u[13]), pk(u[14], u[15]));
  }
  __syncthreads();
  {
    const int x = tid & 63, yg = tid >> 6;
    float acc[2][8];
    #pragma unroll
    for (int r = 0; r < 2; ++r)
      #pragma unroll
      for (int o = 0; o < 8; ++o) acc[r][o] = b5[o];
    #pragma unroll
    for (int k = 0; k < 9; ++k) {
      const int ky = k / 3, kx = k % 3;
      const int p = x + kx;
      const int csw = ((p >> 2) & 7) << 4;
      #pragma unroll
      for (int half = 0; half < 2; ++half) {
        float wr[4][16];
        #pragma unroll
        for (int o2 = 0; o2 < 4; ++o2) {
          const int o = half * 4 + o2;
          const uint4 wa = *(const uint4*)&w5b[(k * 8 + o) * 8];      // wave-uniform
          const uint4 wb = *(const uint4*)&w5b[(k * 8 + o) * 8 + 4];
          wr[o2][0]  = bflo(wa.x); wr[o2][1]  = bfhi(wa.x);
          wr[o2][2]  = bflo(wa.y); wr[o2][3]  = bfhi(wa.y);
          wr[o2][4]  = bflo(wa.z); wr[o2][5]  = bfhi(wa.z);
          wr[o2][6]  = bflo(wa.w); wr[o2][7]  = bfhi(wa.w);
          wr[o2][8]  = bflo(wb.x); wr[o2][9]  = bfhi(wb.x);
          wr[o2][10] = bflo(wb.y); wr[o2][11] = bfhi(wb.y);
          wr[o2][12] = bflo(wb.z); wr[o2][13] = bfhi(wb.z);
          wr[o2][14] = bflo(wb.w); wr[o2][15] = bfhi(wb.w);
        }
        #pragma unroll
        for (int r = 0; r < 2; ++r) {
          const int rr = yg + 4 * r;
          if (rr < 5) {
            const int ly = rr + ky;
            const int rowb = ly * 2112;
            const int sw = csw ^ ((ly & 1) << 4);
            const uint4 q0 = *(const uint4*)((const char*)su + rowb + ((p * 32) ^ sw));
            const uint4 q1 = *(const uint4*)((const char*)su + rowb + ((p * 32 + 16) ^ sw));
            float v[16];
            v[0]  = bflo(q0.x); v[1]  = bfhi(q0.x); v[2]  = bflo(q0.y); v[3]  = bfhi(q0.y);
            v[4]  = bflo(q0.z); v[5]  = bfhi(q0.z); v[6]  = bflo(q0.w); v[7]  = bfhi(q0.w);
            v[8]  = bflo(q1.x); v[9]  = bfhi(q1.x); v[10] = bflo(q1.y); v[11] = bfhi(q1.y);
            v[12] = bflo(q1.z); v[13] = bfhi(q1.z); v[14] = bflo(q1.w); v[15] = bfhi(q1.w);
            #pragma unroll
            for (int o2 = 0; o2 < 4; ++o2) {
              float a = acc[r][half * 4 + o2];
              #pragma unroll
              for (int c = 0; c < 16; ++c)
                a += v[c] * wr[o2][c];
              acc[r][half * 4 + o2] = a;
            }
          }
        }
      }
    }
    #pragma unroll
    for (int r = 0; r < 2; ++r) {
      const int rr = yg + 4 * r;
      if (rr < 5) {
        const int Y = y0 + rr;
        uint4 w = make_uint4(pk(lrelu(acc[r][0]), lrelu(acc[r][1])),
                             pk(lrelu(acc[r][2]), lrelu(acc[r][3])),
                             pk(lrelu(acc[r][4]), lrelu(acc[r][5])),
                             pk(lrelu(acc[r][6]), lrelu(acc[r][7])));
        *(uint4*)&h5[(((size_t)b * 50 + Y) * 64 + x) * 8] = w;
      }
    }
  }
}

// ---------------------------------------------------------------- k7 v5 (unchanged)
__global__ __launch_bounds__(256, 1) void k7_inv3_conv6(
    const __hip_bfloat16* __restrict__ h5, const float* __restrict__ wi3,
    const float* __restrict__ bi3, const float* __restrict__ w6,
    const float* __restrict__ b6, float* __restrict__ out) {
  __shared__ uint4 su[12 * 132];   // u3 bf16 ch-last, 25344 B
  __shared__ float wsh[432];       // w6 as [k][o][ci]
  __shared__ float bsh[6];
  const int b = blockIdx.x, yt = blockIdx.y, tid = threadIdx.x;
  const int y0 = 10 * yt;
  for (int i = tid; i < 432; i += 256) {
    const int ci = i & 7, rem = i >> 3, o = rem % 6, k = rem / 6;
    wsh[i] = w6[((o * 8 + ci) * 3 + (k / 3)) * 3 + (k % 3)];
  }
  if (tid < 6) bsh[tid] = b6[tid];
  {
    const int lyp = (tid >> 1) & 1, lxp = tid & 1;
    const int ky = (lyp + 1) & 1, kx = (lxp + 1) & 1;   // y0 even: parity(yy)=lyp
    float wr[8][8];
    #pragma unroll
    for (int ci = 0; ci < 8; ++ci)
      #pragma unroll
      for (int c = 0; c < 8; ++c)
        wr[ci][c] = wi3[((ci * 8 + c) * 2 + ky) * 2 + kx];
    float bs[8];
    #pragma unroll
    for (int c = 0; c < 8; ++c) bs[c] = bi3[c];
    for (int p = tid >> 2; p < 390; p += 64) {
      const int ly = lyp + 2 * (p / 65);
      const int lx = lxp + 2 * (p % 65);
      const int yy = y0 - 1 + ly, xx2 = lx - 1;
      float u[8];
      if ((unsigned)yy < 100u && (unsigned)xx2 < 128u) {
        const uint4 hv = *(const uint4*)&h5[(((size_t)b * 50 + (yy >> 1)) * 64 + (xx2 >> 1)) * 8];
        const float v0 = bflo(hv.x), v1 = bfhi(hv.x), v2 = bflo(hv.y), v3 = bfhi(hv.y);
        const float v4 = bflo(hv.z), v5 = bfhi(hv.z), v6 = bflo(hv.w), v7 = bfhi(hv.w);
        #pragma unroll
        for (int c = 0; c < 8; ++c) {
          float a = bs[c];
          a += v0 * wr[0][c]; a += v1 * wr[1][c]; a += v2 * wr[2][c]; a += v3 * wr[3][c];
          a += v4 * wr[4][c]; a += v5 * wr[5][c]; a += v6 * wr[6][c]; a += v7 * wr[7][c];
          u[c] = lrelu(a);
        }
      } else {
        #pragma unroll
        for (int c = 0; c < 8; ++c) u[c] = 0.f;
      }
      su[ly * 132 + lx] = make_uint4(pk(u[0], u[1]), pk(u[2], u[3]),
                                     pk(u[4], u[5]), pk(u[6], u[7]));
    }
  }
  __syncthreads();
  {
    const int x = tid & 127, yb = tid >> 7;
    float acc[5][6];
    #pragma unroll
    for (int r = 0; r < 5; ++r)
      #pragma unroll
      for (int o = 0; o < 6; ++o) acc[r][o] = bsh[o];
    #pragma unroll
    for (int k = 0; k < 9; ++k) {
      const int ky = k / 3, kx = k % 3;
      float wr[6][8];
      #pragma unroll
      for (int o = 0; o < 6; ++o) {
        const float4 wlo = *(const float4*)&wsh[(k * 6 + o) * 8];
        const float4 whi = *(const float4*)&wsh[(k * 6 + o) * 8 + 4];
        wr[o][0] = wlo.x; wr[o][1] = wlo.y; wr[o][2] = wlo.z; wr[o][3] = wlo.w;
        wr[o][4] = whi.x; wr[o][5] = whi.y; wr[o][6] = whi.z; wr[o][7] = whi.w;
      }
      const int lc = x + kx;
      #pragma unroll
      for (int r = 0; r < 5; ++r) {
        const int lr = yb + 2 * r + ky;
        const uint4 q = su[lr * 132 + lc];
        float v[8];
        v[0] = bflo(q.x); v[1] = bfhi(q.x); v[2] = bflo(q.y); v[3] = bfhi(q.y);
        v[4] = bflo(q.z); v[5] = bfhi(q.z); v[6] = bflo(q.w); v[7] = bfhi(q.w);
        #pragma unroll
        for (int o = 0; o < 6; ++o)
          #pragma unroll
          for (int ci = 0; ci < 8; ++ci)
            acc[r][o] += v[ci] * wr[o][ci];
      }
    }
    #pragma unroll
    for (int r = 0; r < 5; ++r) {
      const int Y = y0 + yb + 2 * r;
      #pragma unroll
      for (int o = 0; o < 6; ++o)
        out[((size_t)(b * 6 + o) * 100 + Y) * 128 + x] = acc[r][o];
    }
  }
}

// ---------------------------------------------------------------- launch
extern "C" void kernel_launch(void* const* d_in, const int* in_sizes, int n_in,
                              void* d_out, int out_size, void* d_ws, size_t ws_size,
                              hipStream_t stream) {
  const float* x    = (const float*)d_in[0];
  const float* eps  = (const float*)d_in[1];
  const float* w1   = (const float*)d_in[2];
  const float* b1   = (const float*)d_in[3];
  const float* w2   = (const float*)d_in[4];
  const float* b2   = (const float*)d_in[5];
  const float* w3   = (const float*)d_in[6];
  const float* b3   = (const float*)d_in[7];
  const float* wmu  = (const float*)d_in[8];
  const float* bmu  = (const float*)d_in[9];
  const float* wlv  = (const float*)d_in[10];
  const float* blv  = (const float*)d_in[11];
  const float* wlin = (const float*)d_in[12];
  const float* blin = (const float*)d_in[13];
  const float* wi1  = (const float*)d_in[14];
  const float* bi1  = (const float*)d_in[15];
  const float* w4   = (const float*)d_in[16];
  const float* b4   = (const float*)d_in[17];
  const float* wi2  = (const float*)d_in[18];
  const float* bi2  = (const float*)d_in[19];
  const float* w5   = (const float*)d_in[20];
  const float* b5   = (const float*)d_in[21];
  const float* wi3  = (const float*)d_in[22];
  const float* bi3  = (const float*)d_in[23];
  const float* w6   = (const float*)d_in[24];
  const float* b6   = (const float*)d_in[25];

  char* wsb = (char*)d_ws;
  __hip_bfloat16* p1 = (__hip_bfloat16*)wsb;          // region A
  __hip_bfloat16* h5 = (__hip_bfloat16*)wsb;          // region A (alias, p1 dead)
  float* p2  = (float*)(wsb + BYTE_B);                // region B
  float* h4  = (float*)(wsb + BYTE_B);                // region B (alias, p2 dead)
  float* p3  = (float*)(wsb + BYTE_C);
  float* dec = (float*)(wsb + BYTE_D);
  float* out = (float*)d_out;                         // OUTPUT IS FLOAT32

  const size_t off_z   = (size_t)out_size - 32768;
  const size_t off_kld = off_z - 256;
  const size_t off_lv  = off_kld - 32768;
  const size_t off_mu  = off_lv - 32768;

  k1_conv1_pool<<<dim3(BATCH, 25), 256, 0, stream>>>(x, w1, b1, p1);
  k2_conv2_pool<<<dim3(BATCH, 10), 256, 0, stream>>>(p1, w2, b2, p2);
  k3_conv3_pool<<<dim3(BATCH, 2), 256, 0, stream>>>(p2, w3, b3, p3);
  k4_latent<<<dim3(BATCH), 64, 0, stream>>>(p3, eps, wmu, bmu, wlv, blv, wlin, blin,
                                            dec, out, off_mu, off_lv, off_kld, off_z);
  k5_inv1_conv4<<<dim3(BATCH, 2), 256, 0, stream>>>(dec, wi1, bi1, w4, b4, h4);
  k6_inv2_conv5<<<dim3(BATCH, 10), 256, 0, stream>>>(h4, wi2, bi2, w5, b5, h5);
  k7_inv3_conv6<<<dim3(BATCH, 10), 256, 0, stream>>>(h5, wi3, bi3, w6, b6, out);
}

// Round 34
// 484.728 us; speedup vs baseline: 1.0665x; 1.0665x over previous
//
#include <hip/hip_runtime.h>
#include <hip/hip_bf16.h>

#define DEV __device__ __forceinline__

static DEV float lrelu(float v) { return v >= 0.f ? v : 0.01f * v; }
static DEV float bflo(unsigned u) { return __uint_as_float(u << 16); }
static DEV float bfhi(unsigned u) { return __uint_as_float(u & 0xffff0000u); }
static DEV unsigned short f2bf(float f) {
  unsigned u = __float_as_uint(f);
  return (unsigned short)((u + 0x7FFF + ((u >> 16) & 1)) >> 16);  // RNE
}
static DEV unsigned pk(float a, float b) {
  return (unsigned)f2bf(a) | ((unsigned)f2bf(b) << 16);
}

constexpr int BATCH = 256;

// ---- compact workspace layout (bytes) ----
constexpr size_t BYTE_B = 13107200;
constexpr size_t BYTE_C = 18350080;
constexpr size_t BYTE_D = 19398656;

// ---------------------------------------------------------------- k1 v8 (RESTORED; v9 y-merge+shuffle refuted:
// lane-stride-2 ds_read_b128 conflicts + serial shfl chain, +30us)
__global__ __launch_bounds__(256, 1) void k1_conv1_pool(
    const float* __restrict__ x, const float* __restrict__ w1,
    const float* __restrict__ b1, __hip_bfloat16* __restrict__ p1) {
  __shared__ uint4 xs[4 * 132];      // 4 rows x 130(+2 pad) pos x 6ch bf16, 8448 B
  __shared__ float4 pc[512];         // conv out [cy2][cx128][co8] f32, 8192 B
  __shared__ float wsh[576];         // [k9][co8][ci8] f32 (ci 6,7 zero), 2304 B
  __shared__ float bsh[8];
  const int b = blockIdx.x, yt = blockIdx.y, tid = threadIdx.x;
  for (int i = tid; i < 576; i += 256) {
    const int ci = i & 7, co = (i >> 3) & 7, k = i >> 6;
    wsh[i] = (ci < 6) ? w1[(co * 6 + ci) * 9 + k] : 0.f;
  }
  if (tid < 8) bsh[tid] = b1[tid];
  for (int p = tid; p < 520; p += 256) {
    const int lx = p % 130, ly = p / 130;
    const int gy = 2 * yt - 1 + ly, gx = lx - 1;
    float v[6];
    if ((unsigned)gy < 100u && (unsigned)gx < 128u) {
      #pragma unroll
      for (int c = 0; c < 6; ++c) v[c] = x[((size_t)(b * 6 + c) * 100 + gy) * 128 + gx];
    } else {
      #pragma unroll
      for (int c = 0; c < 6; ++c) v[c] = 0.f;
    }
    xs[ly * 132 + lx] = make_uint4(pk(v[0], v[1]), pk(v[2], v[3]), pk(v[4], v[5]), 0u);
  }
  __syncthreads();
  {
    const int cy = tid >> 7, cx = tid & 127;
    float ev[8];
    #pragma unroll
    for (int co = 0; co < 8; ++co) ev[co] = bsh[co];
    #pragma unroll
    for (int k = 0; k < 9; ++k) {
      const int ky = k / 3, kx = k % 3;
      const uint4 q = xs[(cy + ky) * 132 + (cx + kx)];
      const float i0 = bflo(q.x), i1 = bfhi(q.x);
      const float i2 = bflo(q.y), i3 = bfhi(q.y);
      const float i4 = bflo(q.z), i5 = bfhi(q.z);
      #pragma unroll
      for (int co = 0; co < 8; ++co) {
        const float4 wlo = *(const float4*)&wsh[(k * 8 + co) * 8];      // wave-uniform f32
        const float2 whi = *(const float2*)&wsh[(k * 8 + co) * 8 + 4];
        float a = ev[co];
        a += i0 * wlo.x; a += i1 * wlo.y;
        a += i2 * wlo.z; a += i3 * wlo.w;
        a += i4 * whi.x; a += i5 * whi.y;
        ev[co] = a;
      }
    }
    float4* pp = &pc[(cy * 128 + cx) * 2];
    pp[0] = make_float4(lrelu(ev[0]), lrelu(ev[1]), lrelu(ev[2]), lrelu(ev[3]));
    pp[1] = make_float4(lrelu(ev[4]), lrelu(ev[5]), lrelu(ev[6]), lrelu(ev[7]));
  }
  __syncthreads();
  if (tid < 64) {
    const int ox = tid;
    const float4 a0 = pc[(2 * ox) * 2],       a1 = pc[(2 * ox) * 2 + 1];
    const float4 b0 = pc[(2 * ox + 1) * 2],   b1 = pc[(2 * ox + 1) * 2 + 1];
    const float4 c0 = pc[(128 + 2 * ox) * 2], c1 = pc[(128 + 2 * ox) * 2 + 1];
    const float4 d0 = pc[(128 + 2 * ox + 1) * 2], d1 = pc[(128 + 2 * ox + 1) * 2 + 1];
    float m[8];
    m[0] = fmaxf(fmaxf(a0.x, b0.x), fmaxf(c0.x, d0.x));
    m[1] = fmaxf(fmaxf(a0.y, b0.y), fmaxf(c0.y, d0.y));
    m[2] = fmaxf(fmaxf(a0.z, b0.z), fmaxf(c0.z, d0.z));
    m[3] = fmaxf(fmaxf(a0.w, b0.w), fmaxf(c0.w, d0.w));
    m[4] = fmaxf(fmaxf(a1.x, b1.x), fmaxf(c1.x, d1.x));
    m[5] = fmaxf(fmaxf(a1.y, b1.y), fmaxf(c1.y, d1.y));
    m[6] = fmaxf(fmaxf(a1.z, b1.z), fmaxf(c1.z, d1.z));
    m[7] = fmaxf(fmaxf(a1.w, b1.w), fmaxf(c1.w, d1.w));
    #pragma unroll
    for (int co = 0; co < 8; ++co)
      p1[((size_t)(b * 8 + co) * 50 + yt) * 64 + ox] = __float2bfloat16(m[co]);
  }
}

// ---------------------------------------------------------------- k2 v2b (best)
__global__ __launch_bounds__(256, 1) void k2_conv2_pool(
    const __hip_bfloat16* __restrict__ p1, const float* __restrict__ w2,
    const float* __restrict__ b2, float* __restrict__ p2) {
  __shared__ float4 s1[1904];        // 7 * 272 float4 = 30464 B
  __shared__ float wsh[1152];        // [k9][co16][ci8]
  __shared__ float bsh[16];
  const int b = blockIdx.x, yt = blockIdx.y, tid = threadIdx.x;
  for (int i = tid; i < 1152; i += 256) {
    const int ci = i & 7, co = (i >> 3) & 15, k = i >> 7;
    wsh[i] = w2[(co * 8 + ci) * 9 + k];
  }
  if (tid < 16) bsh[tid] = b2[tid];
  for (int p = tid; p < 462; p += 256) {
    const int lx = p % 66, ly = p / 66;
    const int gy = 5 * yt - 1 + ly, gx = lx - 1;
    float v[8];
    if ((unsigned)gy < 50u && (unsigned)gx < 64u) {
      #pragma unroll
      for (int c = 0; c < 8; ++c)
        v[c] = __bfloat162float(p1[((size_t)(b * 8 + c) * 50 + gy) * 64 + gx]);
    } else {
      #pragma unroll
      for (int c = 0; c < 8; ++c) v[c] = 0.f;
    }
    const int base = ly * 4352;   // 136 positions * 32 B stride
    const int sw = (((lx >> 2) & 7) << 4) ^ ((ly & 1) << 4);
    *(float4*)((char*)s1 + base + ((lx * 32) ^ sw)) = make_float4(v[0], v[1], v[2], v[3]);
    *(float4*)((char*)s1 + base + ((lx * 32 + 16) ^ sw)) = make_float4(v[4], v[5], v[6], v[7]);
  }
  __syncthreads();
  {
    const int ox = tid & 31, cog = tid >> 5;   // co pair {2cog, 2cog+1}
    const int co0 = cog * 2;
    float ev[2][5][2];
    #pragma unroll
    for (int j = 0; j < 2; ++j) {
      const float bv = bsh[co0 + j];
      #pragma unroll
      for (int dy = 0; dy < 5; ++dy) { ev[j][dy][0] = bv; ev[j][dy][1] = bv; }
    }
    #pragma unroll
    for (int k = 0; k < 9; ++k) {
      const int ky = k / 3, kx = k % 3;
      float wr[2][8];
      #pragma unroll
      for (int j = 0; j < 2; ++j) {
        const float4 lo = *(const float4*)&wsh[(k * 16 + co0 + j) * 8];
        const float4 hi = *(const float4*)&wsh[(k * 16 + co0 + j) * 8 + 4];
        wr[j][0] = lo.x; wr[j][1] = lo.y; wr[j][2] = lo.z; wr[j][3] = lo.w;
        wr[j][4] = hi.x; wr[j][5] = hi.y; wr[j][6] = hi.z; wr[j][7] = hi.w;
      }
      #pragma unroll
      for (int dy = 0; dy < 5; ++dy) {
        const int lr = dy + ky;
        const int base = lr * 4352;
        const int rsw = (lr & 1) << 4;
        float in2[2][8];
        #pragma unroll
        for (int dx = 0; dx < 2; ++dx) {
          const int lc = 2 * ox + dx + kx;
          const int sw = (((lc >> 2) & 7) << 4) ^ rsw;
          const float4 lo = *(const float4*)((const char*)s1 + base + ((lc * 32) ^ sw));
          const float4 hi = *(const float4*)((const char*)s1 + base + ((lc * 32 + 16) ^ sw));
          in2[dx][0] = lo.x; in2[dx][1] = lo.y; in2[dx][2] = lo.z; in2[dx][3] = lo.w;
          in2[dx][4] = hi.x; in2[dx][5] = hi.y; in2[dx][6] = hi.z; in2[dx][7] = hi.w;
        }
        #pragma unroll
        for (int j = 0; j < 2; ++j)
          #pragma unroll
          for (int dx = 0; dx < 2; ++dx)
            #pragma unroll
            for (int ci = 0; ci < 8; ++ci)
              ev[j][dy][dx] += in2[dx][ci] * wr[j][ci];
      }
    }
    #pragma unroll
    for (int j = 0; j < 2; ++j) {
      float m = -1e30f;
      #pragma unroll
      for (int dy = 0; dy < 5; ++dy)
        #pragma unroll
        for (int dx = 0; dx < 2; ++dx)
          m = fmaxf(m, lrelu(ev[j][dy][dx]));
      p2[((size_t)(b * 16 + co0 + j) * 10 + yt) * 32 + ox] = m;
    }
  }
}

// ---------------------------------------------------------------- k3 v2 (best)
__global__ __launch_bounds__(256) void k3_conv3_pool(
    const float* __restrict__ p2, const float* __restrict__ w3,
    const float* __restrict__ b3, float* __restrict__ p3) {
  __shared__ float s2[16][7][34];    // p2 rows 5oh-1 .. 5oh+5, 15232 B
  __shared__ float wsh[4608];
  __shared__ float bsh[32];
  const int b = blockIdx.x, oh = blockIdx.y, tid = threadIdx.x;
  for (int i = tid; i < 4608; i += 256) wsh[i] = w3[i];
  if (tid < 32) bsh[tid] = b3[tid];
  for (int i = tid; i < 16 * 7 * 34; i += 256) {
    int col = i % 34, rem = i / 34, r = rem % 7, c = rem / 7;
    int gy = 5 * oh - 1 + r, gx = col - 1;
    float v = 0.f;
    if ((unsigned)gy < 10u && (unsigned)gx < 32u)
      v = p2[((b * 16 + c) * 10 + gy) * 32 + gx];
    s2[c][r][col] = v;
  }
  __syncthreads();
  for (int i = tid; i < 512; i += 256) {
    int ow = i & 15, co = i >> 4;
    float m = -1e30f;
    for (int dy = 0; dy < 5; ++dy)
      #pragma unroll
      for (int dx = 0; dx < 2; ++dx) {
        int cx = 2 * ow + dx;
        float acc = bsh[co];
        #pragma unroll
        for (int ci = 0; ci < 16; ++ci)
          #pragma unroll
          for (int ky = 0; ky < 3; ++ky)
            #pragma unroll
            for (int kx = 0; kx < 3; ++kx)
              acc += s2[ci][dy + ky][cx + kx] * wsh[(co * 16 + ci) * 9 + ky * 3 + kx];
        m = fmaxf(m, lrelu(acc));
      }
    p3[((b * 32 + co) * 2 + oh) * 16 + ow] = m;
  }
}

// ---------------------------------------------------------------- k4 (unchanged)
__global__ __launch_bounds__(64) void k4_latent(
    const float* __restrict__ p3, const float* __restrict__ eps,
    const float* __restrict__ wmu, const float* __restrict__ bmu,
    const float* __restrict__ wlv, const float* __restrict__ blv,
    const float* __restrict__ wlin, const float* __restrict__ blin,
    float* __restrict__ dec, float* __restrict__ out,
    size_t off_mu, size_t off_lv, size_t off_kld, size_t off_z) {
  const int b = blockIdx.x, t = threadIdx.x;
  __shared__ float skld[32];
  if (t < 32) {
    const int h = t >> 4, w = t & 15;
    float f[32];
    #pragma unroll
    for (int c = 0; c < 32; ++c) f[c] = p3[((b * 32 + c) * 2 + h) * 16 + w];
    const int n = b * 32 + t;
    float mu[4], lv[4], zz[4];
    #pragma unroll
    for (int j = 0; j < 4; ++j) {
      float m = bmu[j], l = blv[j];
      #pragma unroll
      for (int c = 0; c < 32; ++c) { m += f[c] * wmu[c * 4 + j]; l += f[c] * wlv[c * 4 + j]; }
      mu[j] = m; lv[j] = l;
      zz[j] = m + eps[n * 4 + j] * expf(0.5f * l);
    }
    float kc = 0.f;
    #pragma unroll
    for (int j = 0; j < 4; ++j) kc += 1.f + lv[j] - mu[j] * mu[j] - expf(lv[j]);
    skld[t] = -0.5f * kc;
    #pragma unroll
    for (int j = 0; j < 4; ++j) {
      out[off_mu + n * 4 + j] = mu[j];
      out[off_lv + n * 4 + j] = lv[j];
      out[off_z  + n * 4 + j] = zz[j];
    }
    for (int co = 0; co < 32; ++co) {
      float d = blin[co];
      #pragma unroll
      for (int j = 0; j < 4; ++j) d += zz[j] * wlin[j * 32 + co];
      dec[((b * 32 + co) * 2 + h) * 16 + w] = d;
    }
  }
  __syncthreads();
  if (t == 0) {
    float s = 0.f;
    for (int i = 0; i < 32; ++i) s += skld[i];
    out[off_kld + b] = s * (1.f / 32.f);
  }
}

// ---------------------------------------------------------------- k5 v2 (best)
__global__ __launch_bounds__(256) void k5_inv1_conv4(
    const float* __restrict__ dec, const float* __restrict__ wi1,
    const float* __restrict__ bi1, const float* __restrict__ w4,
    const float* __restrict__ b4, float* __restrict__ h4) {
  __shared__ float sdec[1024];       // dec [32][2][16] f32, 4 KB
  __shared__ float su1[32][7][34];   // u1 rows y0-1..y0+5 (+x halo), 30464 B
  const int b = blockIdx.x, yt = blockIdx.y, tid = threadIdx.x;
  const int y0 = 5 * yt;
  for (int i = tid; i < 1024; i += 256) sdec[i] = dec[b * 1024 + i];
  __syncthreads();
  for (int i = tid; i < 32 * 7 * 34; i += 256) {
    int col = i % 34, rem = i / 34, ly = rem % 7, c = rem / 7;
    int X = col - 1, Y = y0 - 1 + ly;
    float v = 0.f;
    if ((unsigned)Y < 10u && (unsigned)X < 32u) {
      int hh = Y / 5, ky = Y % 5, wp = X >> 1, kx = X & 1;
      float acc = bi1[c];
      #pragma unroll
      for (int ci = 0; ci < 32; ++ci)
        acc += sdec[(ci * 2 + hh) * 16 + wp] * wi1[((ci * 32 + c) * 5 + ky) * 2 + kx];
      v = lrelu(acc);
    }
    su1[c][ly][col] = v;
  }
  __syncthreads();
  for (int i = tid; i < 16 * 5 * 32; i += 256) {
    int X = i & 31, rem = i >> 5, rr = rem % 5, o = rem / 5;
    float acc = b4[o];
    for (int c = 0; c < 32; ++c)
      #pragma unroll
      for (int ky = 0; ky < 3; ++ky)
        #pragma unroll
        for (int kx = 0; kx < 3; ++kx)
          acc += su1[c][rr + ky][X + kx] * w4[((o * 32 + c) * 3 + ky) * 3 + kx];
    h4[((b * 16 + o) * 10 + y0 + rr) * 32 + X] = lrelu(acc);
  }
}

// ---------------------------------------------------------------- k6 v6 (best)
__global__ __launch_bounds__(256, 1) void k6_inv2_conv5(
    const float* __restrict__ h4, const float* __restrict__ wi2,
    const float* __restrict__ bi2, const float* __restrict__ w5,
    const float* __restrict__ b5, __hip_bfloat16* __restrict__ h5) {
  __shared__ uint4 su[924];           // u2 bf16 ch-last [7][66][16], swizzled, 14784 B
  __shared__ unsigned sh4b[3][32][12];// h4 ch-last bf16 pairs (8 used + 4 pad), 4608 B
  __shared__ unsigned wcl[1280];      // wi2 bf16 pairs [ci16][tap10][cp8], 5120 B
  __shared__ unsigned w5b[576];       // w5 bf16 pairs [k9][o8][cp8], 2304 B
  const int b = blockIdx.x, yt = blockIdx.y, tid = threadIdx.x;
  const int y0 = 5 * yt;
  const int r0 = (yt == 0) ? 0 : (yt - 1);
  for (int i = tid; i < 768; i += 256) {
    const int cp = i & 7, hc = (i >> 3) & 31, r = i >> 8;
    const int gr = r0 + r;
    const int c0 = cp * 2;
    float va = 0.f, vb = 0.f;
    if (gr < 10) {
      va = h4[((b * 16 + c0) * 10 + gr) * 32 + hc];
      vb = h4[((b * 16 + c0 + 1) * 10 + gr) * 32 + hc];
    }
    sh4b[r][hc][cp] = pk(va, vb);
  }
  for (int i = tid; i < 1280; i += 256) {
    const int cp = i & 7, ci = (i >> 3) & 15, tap = i >> 7;
    const int ky = tap >> 1, kx = tap & 1;
    const int c0 = cp * 2;
    const float wa = wi2[((ci * 16 + c0) * 5 + ky) * 2 + kx];
    const float wb = wi2[((ci * 16 + c0 + 1) * 5 + ky) * 2 + kx];
    wcl[(ci * 10 + tap) * 8 + cp] = pk(wa, wb);   // [ci][tap][cp]
  }
  for (int i = tid; i < 576; i += 256) {
    const int cp = i & 7, o = (i >> 3) & 7, k = i >> 6;
    const int c0 = cp * 2;
    w5b[i] = pk(w5[((o * 16 + c0) * 3 + (k / 3)) * 3 + (k % 3)],
                w5[((o * 16 + c0 + 1) * 3 + (k / 3)) * 3 + (k % 3)]);
  }
  __syncthreads();
  for (int pos = tid; pos < 462; pos += 256) {
    const int lx = pos % 66, ly = pos / 66;
    const int Y = y0 - 1 + ly, X = lx - 1;
    float u[16];
    if ((unsigned)Y < 50u && (unsigned)X < 64u) {
      const int hr = Y / 5 - r0, ky = Y % 5, hc = X >> 1, kx = X & 1;
      const int tap = ky * 2 + kx;
      #pragma unroll
      for (int c = 0; c < 16; ++c) u[c] = bi2[c];
      float hv[16];
      {
        const uint4 t0 = *(const uint4*)&sh4b[hr][hc][0];
        const uint4 t1 = *(const uint4*)&sh4b[hr][hc][4];
        hv[0]  = bflo(t0.x); hv[1]  = bfhi(t0.x);
        hv[2]  = bflo(t0.y); hv[3]  = bfhi(t0.y);
        hv[4]  = bflo(t0.z); hv[5]  = bfhi(t0.z);
        hv[6]  = bflo(t0.w); hv[7]  = bfhi(t0.w);
        hv[8]  = bflo(t1.x); hv[9]  = bfhi(t1.x);
        hv[10] = bflo(t1.y); hv[11] = bfhi(t1.y);
        hv[12] = bflo(t1.z); hv[13] = bfhi(t1.z);
        hv[14] = bflo(t1.w); hv[15] = bfhi(t1.w);
      }
      #pragma unroll
      for (int ci = 0; ci < 16; ++ci) {
        const uint4 wq0 = *(const uint4*)&wcl[(ci * 10 + tap) * 8];      // [ci][tap]
        const uint4 wq1 = *(const uint4*)&wcl[(ci * 10 + tap) * 8 + 4];
        const float h = hv[ci];
        u[0]  += h * bflo(wq0.x); u[1]  += h * bfhi(wq0.x);
        u[2]  += h * bflo(wq0.y); u[3]  += h * bfhi(wq0.y);
        u[4]  += h * bflo(wq0.z); u[5]  += h * bfhi(wq0.z);
        u[6]  += h * bflo(wq0.w); u[7]  += h * bfhi(wq0.w);
        u[8]  += h * bflo(wq1.x); u[9]  += h * bfhi(wq1.x);
        u[10] += h * bflo(wq1.y); u[11] += h * bfhi(wq1.y);
        u[12] += h * bflo(wq1.z); u[13] += h * bfhi(wq1.z);
        u[14] += h * bflo(wq1.w); u[15] += h * bfhi(wq1.w);
      }
      #pragma unroll
      for (int c = 0; c < 16; ++c) u[c] = lrelu(u[c]);
    } else {
      #pragma unroll
      for (int c = 0; c < 16; ++c) u[c] = 0.f;
    }
    const int sw = (((lx >> 2) & 7) << 4) ^ ((ly & 1) << 4);
    *(uint4*)((char*)su + ly * 2112 + ((lx * 32) ^ sw)) =
        make_uint4(pk(u[0], u[1]), pk(u[2], u[3]), pk(u[4], u[5]), pk(u[6], u[7]));
    *(uint4*)((char*)su + ly * 2112 + ((lx * 32 + 16) ^ sw)) =
        make_uint4(pk(u[8], u[9]), pk(u[10], u[11]), pk(u[12], u[13]), pk(u[14], u[15]));
  }
  __syncthreads();
  {
    const int x = tid & 63, yg = tid >> 6;
    float acc[2][8];
    #pragma unroll
    for (int r = 0; r < 2; ++r)
      #pragma unroll
      for (int o = 0; o < 8; ++o) acc[r][o] = b5[o];
    #pragma unroll
    for (int k = 0; k < 9; ++k) {
      const int ky = k / 3, kx = k % 3;
      const int p = x + kx;
      const int csw = ((p >> 2) & 7) << 4;
      #pragma unroll
      for (int half = 0; half < 2; ++half) {
        float wr[4][16];
        #pragma unroll
        for (int o2 = 0; o2 < 4; ++o2) {
          const int o = half * 4 + o2;
          const uint4 wa = *(const uint4*)&w5b[(k * 8 + o) * 8];      // wave-uniform
          const uint4 wb = *(const uint4*)&w5b[(k * 8 + o) * 8 + 4];
          wr[o2][0]  = bflo(wa.x); wr[o2][1]  = bfhi(wa.x);
          wr[o2][2]  = bflo(wa.y); wr[o2][3]  = bfhi(wa.y);
          wr[o2][4]  = bflo(wa.z); wr[o2][5]  = bfhi(wa.z);
          wr[o2][6]  = bflo(wa.w); wr[o2][7]  = bfhi(wa.w);
          wr[o2][8]  = bflo(wb.x); wr[o2][9]  = bfhi(wb.x);
          wr[o2][10] = bflo(wb.y); wr[o2][11] = bfhi(wb.y);
          wr[o2][12] = bflo(wb.z); wr[o2][13] = bfhi(wb.z);
          wr[o2][14] = bflo(wb.w); wr[o2][15] = bfhi(wb.w);
        }
        #pragma unroll
        for (int r = 0; r < 2; ++r) {
          const int rr = yg + 4 * r;
          if (rr < 5) {
            const int ly = rr + ky;
            const int rowb = ly * 2112;
            const int sw = csw ^ ((ly & 1) << 4);
            const uint4 q0 = *(const uint4*)((const char*)su + rowb + ((p * 32) ^ sw));
            const uint4 q1 = *(const uint4*)((const char*)su + rowb + ((p * 32 + 16) ^ sw));
            float v[16];
            v[0]  = bflo(q0.x); v[1]  = bfhi(q0.x); v[2]  = bflo(q0.y); v[3]  = bfhi(q0.y);
            v[4]  = bflo(q0.z); v[5]  = bfhi(q0.z); v[6]  = bflo(q0.w); v[7]  = bfhi(q0.w);
            v[8]  = bflo(q1.x); v[9]  = bfhi(q1.x); v[10] = bflo(q1.y); v[11] = bfhi(q1.y);
            v[12] = bflo(q1.z); v[13] = bfhi(q1.z); v[14] = bflo(q1.w); v[15] = bfhi(q1.w);
            #pragma unroll
            for (int o2 = 0; o2 < 4; ++o2) {
              float a = acc[r][half * 4 + o2];
              #pragma unroll
              for (int c = 0; c < 16; ++c)
                a += v[c] * wr[o2][c];
              acc[r][half * 4 + o2] = a;
            }
          }
        }
      }
    }
    #pragma unroll
    for (int r = 0; r < 2; ++r) {
      const int rr = yg + 4 * r;
      if (rr < 5) {
        const int Y = y0 + rr;
        uint4 w = make_uint4(pk(lrelu(acc[r][0]), lrelu(acc[r][1])),
                             pk(lrelu(acc[r][2]), lrelu(acc[r][3])),
                             pk(lrelu(acc[r][4]), lrelu(acc[r][5])),
                             pk(lrelu(acc[r][6]), lrelu(acc[r][7])));
        *(uint4*)&h5[(((size_t)b * 50 + Y) * 64 + x) * 8] = w;
      }
    }
  }
}

// ---------------------------------------------------------------- k7 v5 (best)
__global__ __launch_bounds__(256, 1) void k7_inv3_conv6(
    const __hip_bfloat16* __restrict__ h5, const float* __restrict__ wi3,
    const float* __restrict__ bi3, const float* __restrict__ w6,
    const float* __restrict__ b6, float* __restrict__ out) {
  __shared__ uint4 su[12 * 132];   // u3 bf16 ch-last, 25344 B
  __shared__ float wsh[432];       // w6 as [k][o][ci]
  __shared__ float bsh[6];
  const int b = blockIdx.x, yt = blockIdx.y, tid = threadIdx.x;
  const int y0 = 10 * yt;
  for (int i = tid; i < 432; i += 256) {
    const int ci = i & 7, rem = i >> 3, o = rem % 6, k = rem / 6;
    wsh[i] = w6[((o * 8 + ci) * 3 + (k / 3)) * 3 + (k % 3)];
  }
  if (tid < 6) bsh[tid] = b6[tid];
  {
    const int lyp = (tid >> 1) & 1, lxp = tid & 1;
    const int ky = (lyp + 1) & 1, kx = (lxp + 1) & 1;   // y0 even: parity(yy)=lyp
    float wr[8][8];
    #pragma unroll
    for (int ci = 0; ci < 8; ++ci)
      #pragma unroll
      for (int c = 0; c < 8; ++c)
        wr[ci][c] = wi3[((ci * 8 + c) * 2 + ky) * 2 + kx];
    float bs[8];
    #pragma unroll
    for (int c = 0; c < 8; ++c) bs[c] = bi3[c];
    for (int p = tid >> 2; p < 390; p += 64) {
      const int ly = lyp + 2 * (p / 65);
      const int lx = lxp + 2 * (p % 65);
      const int yy = y0 - 1 + ly, xx2 = lx - 1;
      float u[8];
      if ((unsigned)yy < 100u && (unsigned)xx2 < 128u) {
        const uint4 hv = *(const uint4*)&h5[(((size_t)b * 50 + (yy >> 1)) * 64 + (xx2 >> 1)) * 8];
        const float v0 = bflo(hv.x), v1 = bfhi(hv.x), v2 = bflo(hv.y), v3 = bfhi(hv.y);
        const float v4 = bflo(hv.z), v5 = bfhi(hv.z), v6 = bflo(hv.w), v7 = bfhi(hv.w);
        #pragma unroll
        for (int c = 0; c < 8; ++c) {
          float a = bs[c];
          a += v0 * wr[0][c]; a += v1 * wr[1][c]; a += v2 * wr[2][c]; a += v3 * wr[3][c];
          a += v4 * wr[4][c]; a += v5 * wr[5][c]; a += v6 * wr[6][c]; a += v7 * wr[7][c];
          u[c] = lrelu(a);
        }
      } else {
        #pragma unroll
        for (int c = 0; c < 8; ++c) u[c] = 0.f;
      }
      su[ly * 132 + lx] = make_uint4(pk(u[0], u[1]), pk(u[2], u[3]),
                                     pk(u[4], u[5]), pk(u[6], u[7]));
    }
  }
  __syncthreads();
  {
    const int x = tid & 127, yb = tid >> 7;
    float acc[5][6];
    #pragma unroll
    for (int r = 0; r < 5; ++r)
      #pragma unroll
      for (int o = 0; o < 6; ++o) acc[r][o] = bsh[o];
    #pragma unroll
    for (int k = 0; k < 9; ++k) {
      const int ky = k / 3, kx = k % 3;
      float wr[6][8];
      #pragma unroll
      for (int o = 0; o < 6; ++o) {
        const float4 wlo = *(const float4*)&wsh[(k * 6 + o) * 8];
        const float4 whi = *(const float4*)&wsh[(k * 6 + o) * 8 + 4];
        wr[o][0] = wlo.x; wr[o][1] = wlo.y; wr[o][2] = wlo.z; wr[o][3] = wlo.w;
        wr[o][4] = whi.x; wr[o][5] = whi.y; wr[o][6] = whi.z; wr[o][7] = whi.w;
      }
      const int lc = x + kx;
      #pragma unroll
      for (int r = 0; r < 5; ++r) {
        const int lr = yb + 2 * r + ky;
        const uint4 q = su[lr * 132 + lc];
        float v[8];
        v[0] = bflo(q.x); v[1] = bfhi(q.x); v[2] = bflo(q.y); v[3] = bfhi(q.y);
        v[4] = bflo(q.z); v[5] = bfhi(q.z); v[6] = bflo(q.w); v[7] = bfhi(q.w);
        #pragma unroll
        for (int o = 0; o < 6; ++o)
          #pragma unroll
          for (int ci = 0; ci < 8; ++ci)
            acc[r][o] += v[ci] * wr[o][ci];
      }
    }
    #pragma unroll
    for (int r = 0; r < 5; ++r) {
      const int Y = y0 + yb + 2 * r;
      #pragma unroll
      for (int o = 0; o < 6; ++o)
        out[((size_t)(b * 6 + o) * 100 + Y) * 128 + x] = acc[r][o];
    }
  }
}

// ---------------------------------------------------------------- launch
extern "C" void kernel_launch(void* const* d_in, const int* in_sizes, int n_in,
                              void* d_out, int out_size, void* d_ws, size_t ws_size,
                              hipStream_t stream) {
  const float* x    = (const float*)d_in[0];
  const float* eps  = (const float*)d_in[1];
  const float* w1   = (const float*)d_in[2];
  const float* b1   = (const float*)d_in[3];
  const float* w2   = (const float*)d_in[4];
  const float* b2   = (const float*)d_in[5];
  const float* w3   = (const float*)d_in[6];
  const float* b3   = (const float*)d_in[7];
  const float* wmu  = (const float*)d_in[8];
  const float* bmu  = (const float*)d_in[9];
  const float* wlv  = (const float*)d_in[10];
  const float* blv  = (const float*)d_in[11];
  const float* wlin = (const float*)d_in[12];
  const float* blin = (const float*)d_in[13];
  const float* wi1  = (const float*)d_in[14];
  const float* bi1  = (const float*)d_in[15];
  const float* w4   = (const float*)d_in[16];
  const float* b4   = (const float*)d_in[17];
  const float* wi2  = (const float*)d_in[18];
  const float* bi2  = (const float*)d_in[19];
  const float* w5   = (const float*)d_in[20];
  const float* b5   = (const float*)d_in[21];
  const float* wi3  = (const float*)d_in[22];
  const float* bi3  = (const float*)d_in[23];
  const float* w6   = (const float*)d_in[24];
  const float* b6   = (const float*)d_in[25];

  char* wsb = (char*)d_ws;
  __hip_bfloat16* p1 = (__hip_bfloat16*)wsb;          // region A
  __hip_bfloat16* h5 = (__hip_bfloat16*)wsb;          // region A (alias, p1 dead)
  float* p2  = (float*)(wsb + BYTE_B);                // region B
  float* h4  = (float*)(wsb + BYTE_B);                // region B (alias, p2 dead)
  float* p3  = (float*)(wsb + BYTE_C);
  float* dec = (float*)(wsb + BYTE_D);
  float* out = (float*)d_out;                         // OUTPUT IS FLOAT32

  const size_t off_z   = (size_t)out_size - 32768;
  const size_t off_kld = off_z - 256;
  const size_t off_lv  = off_kld - 32768;
  const size_t off_mu  = off_lv - 32768;

  k1_conv1_pool<<<dim3(BATCH, 50), 256, 0, stream>>>(x, w1, b1, p1);
  k2_conv2_pool<<<dim3(BATCH, 10), 256, 0, stream>>>(p1, w2, b2, p2);
  k3_conv3_pool<<<dim3(BATCH, 2), 256, 0, stream>>>(p2, w3, b3, p3);
  k4_latent<<<dim3(BATCH), 64, 0, stream>>>(p3, eps, wmu, bmu, wlv, blv, wlin, blin,
                                            dec, out, off_mu, off_lv, off_kld, off_z);
  k5_inv1_conv4<<<dim3(BATCH, 2), 256, 0, stream>>>(dec, wi1, bi1, w4, b4, h4);
  k6_inv2_conv5<<<dim3(BATCH, 10), 256, 0, stream>>>(h4, wi2, bi2, w5, b5, h5);
  k7_inv3_conv6<<<dim3(BATCH, 10), 256, 0, stream>>>(h5, wi3, bi3, w6, b6, out);
}